// Round 18
// baseline (434.492 us; speedup 1.0000x reference)
//
#include <hip/hip_runtime.h>
#include <hip/hip_bf16.h>
#include <math.h>

#define N_TOK 4096
#define DIM_V 1024
#define NEXP  8
#define HID   4096
#define NSLOT 9216

typedef short  s16x8 __attribute__((ext_vector_type(8)));
typedef unsigned short u16x8 __attribute__((ext_vector_type(8)));
typedef unsigned short u16x4 __attribute__((ext_vector_type(4)));
typedef float  f32x4 __attribute__((ext_vector_type(4)));

// ---------------- workspace layout ----------------
constexpr size_t OFF_XB   = 0;                        // bf16 [4096][1024]
constexpr size_t OFF_WB   = OFF_XB + 8388608;         // bf16 [1024][1024]
constexpr size_t OFF_RK   = OFF_WB + 2097152;         // (unused, kept for layout)
constexpr size_t OFF_KPP  = OFF_RK + 65536;           // f64  [8][1024]  (zeroed)
constexpr size_t OFF_SSQ  = OFF_KPP + 65536;          // f32  [4096]     (zeroed)
constexpr size_t OFF_CNT  = OFF_SSQ + 16384;          // int[8] pad      (zeroed)
constexpr size_t OFF_CUR  = OFF_CNT + 128;            // int[8] pad      (zeroed)
constexpr size_t OFF_TOK  = OFF_CUR + 128;            // int  [9216]     (zeroed)
constexpr size_t OFF_GSL  = OFF_TOK + 36864;          // f32  [9216]     (zeroed)
constexpr size_t ZERO_BEG = OFF_KPP;
constexpr size_t ZERO_LEN = 155904;                   // through GSL end
constexpr size_t OFF_OFFP = ZERO_BEG + ZERO_LEN;      // int [16]
constexpr size_t OFF_IDX2 = OFF_OFFP + 128;           // int [4096][2]
constexpr size_t OFF_G2   = OFF_IDX2 + 32768;         // f32 [4096][2]
constexpr size_t OFF_INV  = OFF_G2 + 32768;           // int [4096][2]
constexpr size_t SMALL_END = OFF_INV + 32768;

constexpr size_t A_OFF_FCB = SMALL_END;                    // bf16 [8][4096][1024]
constexpr size_t A_OFF_PO  = A_OFF_FCB;                    // f32  [9216][1024] (alias; fcb dead by proj)
constexpr size_t A_OFF_PJB = A_OFF_FCB + 67108864;         // bf16 [8][1024][4096]
constexpr size_t A_OFF_H2  = A_OFF_PJB + 67108864;         // bf16 [9216][4096]
constexpr size_t WS_FULL   = A_OFF_H2 + 75497472;          // ~210.3 MiB (proven)

__device__ inline unsigned short f2bf(float f) {
  __hip_bfloat16 h = __float2bfloat16(f);
  return __builtin_bit_cast(unsigned short, h);
}

__device__ __forceinline__ void gload16(const void* g, void* l) {
  __builtin_amdgcn_global_load_lds(
      (const __attribute__((address_space(1))) unsigned int*)g,
      (__attribute__((address_space(3))) unsigned int*)l, 16, 0, 0);
}

// ---------------- x + router_w fp32 -> bf16, plus zero-init (blocks 160..167) ----------------
__global__ __launch_bounds__(256) void k_cvt_xw(
    const float* __restrict__ x, const float* __restrict__ rw,
    unsigned short* __restrict__ xb, unsigned short* __restrict__ wb,
    char* __restrict__ zbase) {
  const int b = (int)blockIdx.x;
  if (b >= 160) {
    const f32x4 zv = {0.f, 0.f, 0.f, 0.f};
    size_t o = ((size_t)(b - 160) * 256 + threadIdx.x) * 16;
    for (; o < ZERO_LEN; o += (size_t)8 * 256 * 16)
      *(f32x4*)(zbase + o) = zv;
    return;
  }
  int u = b * 8;
  const f32x4* s; u16x4* d; int base;
  if (u < 1024) { s = (const f32x4*)x;  d = (u16x4*)xb; base = u; }
  else          { s = (const f32x4*)rw; d = (u16x4*)wb; base = u - 1024; }
  int j = base * 1024 + (int)threadIdx.x;
#pragma unroll 2
  for (int k = 0; k < 8; ++k, j += 1024) {
    f32x4 v0 = __builtin_nontemporal_load(s + j);
    f32x4 v1 = __builtin_nontemporal_load(s + j + 256);
    f32x4 v2 = __builtin_nontemporal_load(s + j + 512);
    f32x4 v3 = __builtin_nontemporal_load(s + j + 768);
    u16x4 o0 = { f2bf(v0.x), f2bf(v0.y), f2bf(v0.z), f2bf(v0.w) };
    u16x4 o1 = { f2bf(v1.x), f2bf(v1.y), f2bf(v1.z), f2bf(v1.w) };
    u16x4 o2 = { f2bf(v2.x), f2bf(v2.y), f2bf(v2.z), f2bf(v2.w) };
    u16x4 o3 = { f2bf(v3.x), f2bf(v3.y), f2bf(v3.z), f2bf(v3.w) };
    __builtin_nontemporal_store(o0, d + j);
    __builtin_nontemporal_store(o1, d + j + 256);
    __builtin_nontemporal_store(o2, d + j + 512);
    __builtin_nontemporal_store(o3, d + j + 768);
  }
}

// ================= MEGA: qt (0..255) | colsum (256..319) | fc_w cvt (320..1343) =================
constexpr int QTG = 256, CSG = 64, CVG = 1024;

__global__ __launch_bounds__(256) void k_mega(
    const unsigned short* __restrict__ xb, const unsigned short* __restrict__ wb,
    float* __restrict__ sumsq,
    const float* __restrict__ W, const float* __restrict__ keys,
    const int* __restrict__ depth, double* __restrict__ kpp,
    const float* __restrict__ fw, unsigned short* __restrict__ fcb) {
  __shared__ alignas(16) char smem[65536];
  const int bid = (int)blockIdx.x;
  const int tid = threadIdx.x;

  if (bid < QTG) {
    constexpr int KD = DIM_V, GNB = DIM_V / 128, NT = KD / 64, q = QTG >> 3;
    const int idp = (bid & 7) * q + (bid >> 3);
    const int n0 = (idp % GNB) * 128, m0 = (idp / GNB) * 128;
    const unsigned short* Bp = wb + (size_t)n0 * KD;
    const int wid = tid >> 6, lane = tid & 63;
    const int wr = (wid >> 1) * 64, wc = (wid & 1) * 64;
    const int rql  = tid >> 3;
    const int swc8 = ((tid & 7) ^ ((tid >> 3) & 7)) * 8;
    const int frow = lane & 15, fsl = lane >> 4, fkey = lane & 7;

    auto stage = [&](int k0s, unsigned db) {
#pragma unroll
      for (int p = 0; p < 4; ++p)
        gload16(xb + (size_t)(m0 + p * 32 + rql) * KD + k0s + swc8,
                smem + db + p * 4096 + wid * 1024);
#pragma unroll
      for (int p = 0; p < 4; ++p)
        gload16(Bp + (size_t)(p * 32 + rql) * KD + k0s + swc8,
                smem + db + 16384 + p * 4096 + wid * 1024);
    };

    f32x4 acc[4][4] = {};
    stage(0, 0);
#pragma unroll 2
    for (int t = 0; t < NT; ++t) {
      int tn = t + 1; if (tn == NT) tn = 0;
      stage(tn * 64, (unsigned)((t + 1) & 1) * 32768u);
      asm volatile("s_waitcnt vmcnt(8)" ::: "memory");
      __builtin_amdgcn_s_barrier();
      __builtin_amdgcn_sched_barrier(0);
      const unsigned Ab = (unsigned)(t & 1) * 32768u, Bb = Ab + 16384u;
      s16x8 af[2][4], bfr[2][4];
#pragma unroll
      for (int kk2 = 0; kk2 < 2; ++kk2) {
        const unsigned so = (unsigned)(((fsl + kk2 * 4) ^ fkey) << 4);
#pragma unroll
        for (int m = 0; m < 4; ++m)
          af[kk2][m] = *(const s16x8*)(smem + Ab + (unsigned)(wr + m * 16 + frow) * 128 + so);
#pragma unroll
        for (int n = 0; n < 4; ++n)
          bfr[kk2][n] = *(const s16x8*)(smem + Bb + (unsigned)(wc + n * 16 + frow) * 128 + so);
      }
      __builtin_amdgcn_s_setprio(1);
#pragma unroll
      for (int kk2 = 0; kk2 < 2; ++kk2)
#pragma unroll
        for (int m = 0; m < 4; ++m)
#pragma unroll
          for (int n = 0; n < 4; ++n)
            acc[m][n] = __builtin_amdgcn_mfma_f32_16x16x32_bf16(af[kk2][m], bfr[kk2][n],
                                                                acc[m][n], 0, 0, 0);
      __builtin_amdgcn_s_setprio(0);
      __builtin_amdgcn_sched_barrier(0);
      __builtin_amdgcn_s_barrier();
    }
#pragma unroll
    for (int m = 0; m < 4; ++m)
#pragma unroll
      for (int j = 0; j < 4; ++j) {
        const int grow = m0 + wr + m * 16 + (lane >> 4) * 4 + j;
        float s = 0.f;
#pragma unroll
        for (int n = 0; n < 4; ++n) { float v = acc[m][n][j]; s += v * v; }
        s += __shfl_xor(s, 1, 64); s += __shfl_xor(s, 2, 64);
        s += __shfl_xor(s, 4, 64); s += __shfl_xor(s, 8, 64);
        if ((lane & 15) == 0) atomicAdd(&sumsq[grow], s);
      }
  } else if (bid < QTG + CSG) {
    double (*rks)[64] = (double(*)[64])smem;
    const int cid = bid - QTG;
    const int d0 = (cid >> 2) * 64;
    if (tid < 64) {
      const int d = d0 + tid;
      const int dep = depth[0];
      const bool lower = d < 512;
      const int i = lower ? d : d - 512;
      double p = pow(10000.0, (double)i / 512.0);
      float invf = 1.0f / (float)p;
      float ff = (float)dep * invf;
      float rr = (float)(15 - dep) * invf;
      float cf  = (float)cos((double)ff);
      float sf  = (float)sin((double)ff);
      float rcf = (float)cos((double)rr);
      float rsf = (float)sin((double)rr);
      for (int e = 0; e < NEXP; ++e) {
        double k1 = (double)keys[e * DIM_V + i];
        double k2 = (double)keys[e * DIM_V + 512 + i];
        rks[e][tid] = lower ? ((double)cf * k1 - (double)rsf * k2)
                            : ((double)sf * k1 + (double)rcf * k2);
      }
    }
    __syncthreads();
    const int j = (cid & 3) * 256 + tid;
    double acc[NEXP] = {};
    for (int dd = 0; dd < 64; ++dd) {
      double w = (double)W[(size_t)(d0 + dd) * DIM_V + j];
#pragma unroll
      for (int e = 0; e < NEXP; ++e) acc[e] += w * rks[e][dd];
    }
    for (int e = 0; e < NEXP; ++e) atomicAdd(&kpp[e * DIM_V + j], acc[e]);
  } else {
    int u = (bid - QTG - CSG) * 8;
    const f32x4* s = (const f32x4*)fw;
    u16x4* d = (u16x4*)fcb;
    int j = u * 1024 + tid;
#pragma unroll 2
    for (int k = 0; k < 8; ++k, j += 1024) {
      f32x4 v0 = __builtin_nontemporal_load(s + j);
      f32x4 v1 = __builtin_nontemporal_load(s + j + 256);
      f32x4 v2 = __builtin_nontemporal_load(s + j + 512);
      f32x4 v3 = __builtin_nontemporal_load(s + j + 768);
      u16x4 o0 = { f2bf(v0.x), f2bf(v0.y), f2bf(v0.z), f2bf(v0.w) };
      u16x4 o1 = { f2bf(v1.x), f2bf(v1.y), f2bf(v1.z), f2bf(v1.w) };
      u16x4 o2 = { f2bf(v2.x), f2bf(v2.y), f2bf(v2.z), f2bf(v2.w) };
      u16x4 o3 = { f2bf(v3.x), f2bf(v3.y), f2bf(v3.z), f2bf(v3.w) };
      __builtin_nontemporal_store(o0, d + j);
      __builtin_nontemporal_store(o1, d + j + 256);
      __builtin_nontemporal_store(o2, d + j + 512);
      __builtin_nontemporal_store(o3, d + j + 768);
    }
  }
}

// ---------------- proj_w fp32 -> bf16, standalone streaming ----------------
__global__ __launch_bounds__(256) void k_cvt_pjb(
    const float* __restrict__ pw, unsigned short* __restrict__ pjb) {
  int u = (int)blockIdx.x * 8;
  const f32x4* s = (const f32x4*)pw;
  u16x4* d = (u16x4*)pjb;
  int j = u * 1024 + (int)threadIdx.x;
#pragma unroll 2
  for (int k = 0; k < 8; ++k, j += 1024) {
    f32x4 v0 = __builtin_nontemporal_load(s + j);
    f32x4 v1 = __builtin_nontemporal_load(s + j + 256);
    f32x4 v2 = __builtin_nontemporal_load(s + j + 512);
    f32x4 v3 = __builtin_nontemporal_load(s + j + 768);
    u16x4 o0 = { f2bf(v0.x), f2bf(v0.y), f2bf(v0.z), f2bf(v0.w) };
    u16x4 o1 = { f2bf(v1.x), f2bf(v1.y), f2bf(v1.z), f2bf(v1.w) };
    u16x4 o2 = { f2bf(v2.x), f2bf(v2.y), f2bf(v2.z), f2bf(v2.w) };
    u16x4 o3 = { f2bf(v3.x), f2bf(v3.y), f2bf(v3.z), f2bf(v3.w) };
    __builtin_nontemporal_store(o0, d + j);
    __builtin_nontemporal_store(o1, d + j + 256);
    __builtin_nontemporal_store(o2, d + j + 512);
    __builtin_nontemporal_store(o3, d + j + 768);
  }
}

// ---------------- gating: fp64 logits, sigmoid, top-2 (standalone, R12-proven) ----------------
__global__ __launch_bounds__(256) void k_gate(const float* __restrict__ x,
                                              const double* __restrict__ kpp,
                                              const float* __restrict__ sumsq,
                                              const float* __restrict__ bias,
                                              int* __restrict__ idx2, float* __restrict__ gates2,
                                              int* __restrict__ counts) {
  int wave = (blockIdx.x * 256 + threadIdx.x) >> 6;
  int lane = threadIdx.x & 63;
  if (wave >= N_TOK) return;
  const float4* xr = (const float4*)(x + (size_t)wave * DIM_V);
  double a[NEXP] = {};
#pragma unroll
  for (int j = 0; j < 4; ++j) {
    int c = lane + 64 * j;
    float4 v = xr[c];
#pragma unroll
    for (int e = 0; e < NEXP; ++e) {
      const double* kp = kpp + (size_t)e * DIM_V + c * 4;
      a[e] += (double)v.x * kp[0] + (double)v.y * kp[1] +
              (double)v.z * kp[2] + (double)v.w * kp[3];
    }
  }
#pragma unroll
  for (int e = 0; e < NEXP; ++e)
    for (int d = 1; d < 64; d <<= 1) a[e] += __shfl_xor(a[e], d, 64);
  if (lane == 0) {
    float s = rsqrtf(sumsq[wave] * (1.0f / 1024.0f) + 1.1920928955078125e-7f);
    float z[NEXP], b[NEXP];
#pragma unroll
    for (int e = 0; e < NEXP; ++e) {
      z[e] = (float)(a[e] * (double)s * (1.0 / 32.0));
      b[e] = z[e] + bias[e];
    }
    int i1 = 0;
    for (int e = 1; e < NEXP; ++e) if (b[e] > b[i1]) i1 = e;
    int i2 = -1;
    for (int e = 0; e < NEXP; ++e) if (e != i1 && (i2 < 0 || b[e] > b[i2])) i2 = e;
    float g1 = 1.f / (1.f + expf(-z[i1]));
    float g2 = 1.f / (1.f + expf(-z[i2]));
    float sm = fmaxf(g1 + g2, 1e-9f);
    idx2[wave * 2] = i1; idx2[wave * 2 + 1] = i2;
    gates2[wave * 2] = g1 / sm; gates2[wave * 2 + 1] = g2 / sm;
    atomicAdd(&counts[i1], 1); atomicAdd(&counts[i2], 1);
  }
}

// ---------------- scatter tokens to slots (prefix computed locally) ----------------
__global__ void k_scatter(const int* __restrict__ idx2, const float* __restrict__ gates2,
                          const int* __restrict__ counts, int* __restrict__ cursor,
                          int* __restrict__ tok, float* __restrict__ gsl,
                          int* __restrict__ inv, int* __restrict__ offp_out) {
  int off[NEXP + 1];
  off[0] = 0;
  for (int e = 0; e < NEXP; ++e) off[e + 1] = off[e] + ((counts[e] + 127) & ~127);
  int n = blockIdx.x * 256 + threadIdx.x;
  if (blockIdx.x == 0 && threadIdx.x == 0)
    for (int e = 0; e <= NEXP; ++e) offp_out[e] = off[e];
  if (n >= N_TOK) return;
  for (int r = 0; r < 2; ++r) {
    int e = idx2[n * 2 + r];
    int pos = atomicAdd(&cursor[e], 1);
    int slot = off[e] + pos;
    tok[slot] = n; gsl[slot] = gates2[n * 2 + r]; inv[n * 2 + r] = slot;
  }
}

// ================= fc: 256x256x64 grouped GEMM, 8 waves, 128KiB LDS =================
__global__ __launch_bounds__(512) void k_fc256(
    const unsigned short* __restrict__ xb,
    const unsigned short* __restrict__ fcb,
    const int* __restrict__ offp, const int* __restrict__ tok,
    unsigned short* __restrict__ h2) {
  constexpr int KD = DIM_V;     // 1024
  constexpr int NT = KD / 64;   // 16
  const int G = gridDim.x, q = G >> 3;                 // G % 8 == 0
  const int idp = ((int)blockIdx.x & 7) * q + ((int)blockIdx.x >> 3);
  const int bx = idp >> 4;                             // 256-row block index
  const int n0 = (idp & 15) * 256;
  int c = 0, e = 0, m0 = -1;
  for (e = 0; e < NEXP; ++e) {
    int nb = (offp[e + 1] - offp[e] + 255) >> 8;
    if (bx < c + nb) { m0 = offp[e] + (bx - c) * 256; break; }
    c += nb;
  }
  if (m0 < 0) return;
  const int segend = offp[e + 1];
  const unsigned short* Bp = fcb + ((size_t)e * HID + n0) * KD;

  __shared__ alignas(16) char smem[131072];            // 2 x (A 32K + B 32K)
  const int tid = threadIdx.x, wid = tid >> 6, lane = tid & 63;
  const int wr = (wid >> 2) * 128, wcc = (wid & 3) * 64;
  const int swc8 = ((tid & 7) ^ ((tid >> 3) & 7)) * 8;
  const int frow = lane & 15, fsl = lane >> 4, fkey = lane & 7;

  int arow[4];
#pragma unroll
  for (int p = 0; p < 4; ++p) {
    int rr = m0 + p * 64 + (tid >> 3);
    arow[p] = tok[rr < NSLOT ? rr : NSLOT - 1];
  }

  auto stage = [&](int k0s, unsigned db) {
#pragma unroll
    for (int p = 0; p < 4; ++p)
      gload16(xb + (size_t)arow[p] * KD + k0s + swc8,
              smem + db + p * 8192 + wid * 1024);
#pragma unroll
    for (int p = 0; p < 4; ++p)
      gload16(Bp + (size_t)(p * 64 + (tid >> 3)) * KD + k0s + swc8,
              smem + db + 32768 + p * 8192 + wid * 1024);
  };

  f32x4 acc[8][4] = {};
  stage(0, 0);
  for (int t = 0; t < NT; ++t) {
    int tn = t + 1; if (tn == NT) tn = 0;
    stage(tn * 64, (unsigned)((t + 1) & 1) * 65536u);
    asm volatile("s_waitcnt vmcnt(8)" ::: "memory");
    __builtin_amdgcn_s_barrier();
    __builtin_amdgcn_sched_barrier(0);
    const unsigned Ab = (unsigned)(t & 1) * 65536u, Bb = Ab + 32768u;
#pragma unroll
    for (int kk2 = 0; kk2 < 2; ++kk2) {
      const unsigned so = (unsigned)(((fsl + kk2 * 4) ^ fkey) << 4);
      s16x8 af[8], bfr[4];
#pragma unroll
      for (int m = 0; m < 8; ++m)
        af[m] = *(const s16x8*)(smem + Ab + (unsigned)(wr + m * 16 + frow) * 128 + so);
#pragma unroll
      for (int n = 0; n < 4; ++n)
        bfr[n] = *(const s16x8*)(smem + Bb + (unsigned)(wcc + n * 16 + frow) * 128 + so);
      __builtin_amdgcn_s_setprio(1);
#pragma unroll
      for (int m = 0; m < 8; ++m)
#pragma unroll
        for (int n = 0; n < 4; ++n)
          acc[m][n] = __builtin_amdgcn_mfma_f32_16x16x32_bf16(af[m], bfr[n], acc[m][n], 0, 0, 0);
      __builtin_amdgcn_s_setprio(0);
    }
    __builtin_amdgcn_sched_barrier(0);
    __builtin_amdgcn_s_barrier();
  }
#pragma unroll
  for (int m = 0; m < 8; ++m)
#pragma unroll
    for (int j = 0; j < 4; ++j) {
      const int grow = m0 + wr + m * 16 + (lane >> 4) * 4 + j;
      if (grow < segend) {
#pragma unroll
        for (int n = 0; n < 4; ++n) {
          float v = acc[m][n][j];
          v = v > 0.f ? v * v : 0.f;
          h2[(size_t)grow * HID + n0 + wcc + n * 16 + (lane & 15)] = f2bf(v);
        }
      }
    }
}

// ================= proj: 128x128x64, 4 waves, 2-buf counted-vmcnt (R3-proven) =================
__global__ __launch_bounds__(256) void k_proj(
    const unsigned short* __restrict__ h2,
    const unsigned short* __restrict__ pjb,
    const int* __restrict__ offp, const float* __restrict__ gsl,
    float* __restrict__ po) {
  constexpr int KD  = HID;          // 4096
  constexpr int GNB = DIM_V / 128;  // 8
  constexpr int NT  = KD / 64;      // 64
  const int G = gridDim.x, q = G >> 3;
  const int idp = ((int)blockIdx.x & 7) * q + ((int)blockIdx.x >> 3);
  const int n0 = (idp % GNB) * 128, m0 = (idp / GNB) * 128;
  if (m0 >= offp[NEXP]) return;
  int e = 0; while (e < NEXP - 1 && m0 >= offp[e + 1]) ++e;
  const unsigned short* Bp = pjb + ((size_t)e * DIM_V + n0) * KD;

  __shared__ alignas(16) char smem[65536];
  const int tid = threadIdx.x, wid = tid >> 6, lane = tid & 63;
  const int wr = (wid >> 1) * 64, wc = (wid & 1) * 64;
  const int rql  = tid >> 3;
  const int swc8 = ((tid & 7) ^ ((tid >> 3) & 7)) * 8;
  const int frow = lane & 15, fsl = lane >> 4, fkey = lane & 7;

  auto stage = [&](int k0s, unsigned db) {
#pragma unroll
    for (int p = 0; p < 4; ++p)
      gload16(h2 + (size_t)(m0 + p * 32 + rql) * KD + k0s + swc8,
              smem + db + p * 4096 + wid * 1024);
#pragma unroll
    for (int p = 0; p < 4; ++p)
      gload16(Bp + (size_t)(p * 32 + rql) * KD + k0s + swc8,
              smem + db + 16384 + p * 4096 + wid * 1024);
  };

  f32x4 acc[4][4] = {};
  stage(0, 0);
#pragma unroll 2
  for (int t = 0; t < NT; ++t) {
    int tn = t + 1; if (tn == NT) tn = 0;
    stage(tn * 64, (unsigned)((t + 1) & 1) * 32768u);
    asm volatile("s_waitcnt vmcnt(8)" ::: "memory");
    __builtin_amdgcn_s_barrier();
    __builtin_amdgcn_sched_barrier(0);
    const unsigned Ab = (unsigned)(t & 1) * 32768u, Bb = Ab + 16384u;
    s16x8 af[2][4], bfr[2][4];
#pragma unroll
    for (int kk2 = 0; kk2 < 2; ++kk2) {
      const unsigned so = (unsigned)(((fsl + kk2 * 4) ^ fkey) << 4);
#pragma unroll
      for (int m = 0; m < 4; ++m)
        af[kk2][m] = *(const s16x8*)(smem + Ab + (unsigned)(wr + m * 16 + frow) * 128 + so);
#pragma unroll
      for (int n = 0; n < 4; ++n)
        bfr[kk2][n] = *(const s16x8*)(smem + Bb + (unsigned)(wc + n * 16 + frow) * 128 + so);
    }
    __builtin_amdgcn_s_setprio(1);
#pragma unroll
    for (int kk2 = 0; kk2 < 2; ++kk2)
#pragma unroll
      for (int m = 0; m < 4; ++m)
#pragma unroll
        for (int n = 0; n < 4; ++n)
          acc[m][n] = __builtin_amdgcn_mfma_f32_16x16x32_bf16(af[kk2][m], bfr[kk2][n],
                                                              acc[m][n], 0, 0, 0);
    __builtin_amdgcn_s_setprio(0);
    __builtin_amdgcn_sched_barrier(0);
    __builtin_amdgcn_s_barrier();
  }

#pragma unroll
  for (int m = 0; m < 4; ++m)
#pragma unroll
    for (int j = 0; j < 4; ++j) {
      const int grow = m0 + wr + m * 16 + (lane >> 4) * 4 + j;
      const float g = gsl[grow];
#pragma unroll
      for (int n = 0; n < 4; ++n)
        po[(size_t)grow * DIM_V + n0 + wc + n * 16 + (lane & 15)] = acc[m][n][j] * g;
    }
}

// ---------------- combine: y[n] = po[slot1] + po[slot2] ----------------
__global__ void k_combine(const float* __restrict__ po, const int* __restrict__ inv,
                          float* __restrict__ y) {
  const int total = N_TOK * (DIM_V / 4);
  for (int i = blockIdx.x * blockDim.x + threadIdx.x; i < total;
       i += gridDim.x * blockDim.x) {
    int n = i >> 8, c = i & 255;
    int s1 = inv[n * 2], s2 = inv[n * 2 + 1];
    float4 a = ((const float4*)(po + (size_t)s1 * DIM_V))[c];
    float4 b = ((const float4*)(po + (size_t)s2 * DIM_V))[c];
    float4 o; o.x = a.x + b.x; o.y = a.y + b.y; o.z = a.z + b.z; o.w = a.w + b.w;
    ((float4*)(y + (size_t)n * DIM_V))[c] = o;
  }
}

extern "C" void kernel_launch(void* const* d_in, const int* in_sizes, int n_in,
                              void* d_out, int out_size, void* d_ws, size_t ws_size,
                              hipStream_t stream) {
  if (ws_size < WS_FULL) return;
  const float* x      = (const float*)d_in[0];
  const float* rw     = (const float*)d_in[1];
  const float* keys   = (const float*)d_in[2];
  const float* bias   = (const float*)d_in[3];
  const float* fc_w   = (const float*)d_in[4];
  const float* proj_w = (const float*)d_in[5];
  const int*   depth  = (const int*)d_in[6];
  char* ws = (char*)d_ws;
  unsigned short* xb  = (unsigned short*)(ws + OFF_XB);
  unsigned short* wb  = (unsigned short*)(ws + OFF_WB);
  double* kpp   = (double*)(ws + OFF_KPP);
  float*  ssq   = (float*)(ws + OFF_SSQ);
  int*    cnt   = (int*)(ws + OFF_CNT);
  int*    cur   = (int*)(ws + OFF_CUR);
  int*    tok   = (int*)(ws + OFF_TOK);
  float*  gsl   = (float*)(ws + OFF_GSL);
  int*    offp  = (int*)(ws + OFF_OFFP);
  int*    idx2  = (int*)(ws + OFF_IDX2);
  float*  g2    = (float*)(ws + OFF_G2);
  int*    inv   = (int*)(ws + OFF_INV);
  unsigned short* fcb = (unsigned short*)(ws + A_OFF_FCB);
  unsigned short* pjb = (unsigned short*)(ws + A_OFF_PJB);
  unsigned short* h2  = (unsigned short*)(ws + A_OFF_H2);
  float*  po    = (float*)(ws + A_OFF_PO);
  float*  y     = (float*)d_out;

  k_cvt_xw<<<168, 256, 0, stream>>>(x, rw, xb, wb, ws + ZERO_BEG);
  k_mega<<<QTG + CSG + CVG, 256, 0, stream>>>(xb, wb, ssq, rw, keys, depth, kpp,
                                              fc_w, fcb);
  k_cvt_pjb<<<1024, 256, 0, stream>>>(proj_w, pjb);
  k_gate<<<1024, 256, 0, stream>>>(x, kpp, ssq, bias, idx2, g2, cnt);
  k_scatter<<<16, 256, 0, stream>>>(idx2, g2, cnt, cur, tok, gsl, inv, offp);
  k_fc256<<<dim3(44 * 16), 512, 0, stream>>>(xb, fcb, offp, tok, h2);
  k_proj<<<dim3(72 * 8), 256, 0, stream>>>(h2, pjb, offp, gsl, po);
  k_combine<<<2048, 256, 0, stream>>>(po, inv, y);
}

// Round 19
// 416.564 us; speedup vs baseline: 1.0430x; 1.0430x over previous
//
#include <hip/hip_runtime.h>
#include <hip/hip_bf16.h>
#include <math.h>

#define N_TOK 4096
#define DIM_V 1024
#define NEXP  8
#define HID   4096
#define NSLOT 9216

typedef short  s16x8 __attribute__((ext_vector_type(8)));
typedef unsigned short u16x8 __attribute__((ext_vector_type(8)));
typedef unsigned short u16x4 __attribute__((ext_vector_type(4)));
typedef float  f32x4 __attribute__((ext_vector_type(4)));

// ---------------- workspace layout ----------------
constexpr size_t OFF_XB   = 0;                        // bf16 [4096][1024]
constexpr size_t OFF_WB   = OFF_XB + 8388608;         // bf16 [1024][1024]
constexpr size_t OFF_RK   = OFF_WB + 2097152;         // (unused, kept for layout)
constexpr size_t OFF_KPP  = OFF_RK + 65536;           // f64  [8][1024]  (zeroed)
constexpr size_t OFF_SSQ  = OFF_KPP + 65536;          // f32  [4096]     (zeroed)
constexpr size_t OFF_CNT  = OFF_SSQ + 16384;          // int[8] pad      (zeroed)
constexpr size_t OFF_CUR  = OFF_CNT + 128;            // int[8] pad      (zeroed)
constexpr size_t OFF_TOK  = OFF_CUR + 128;            // int  [9216]     (zeroed)
constexpr size_t OFF_GSL  = OFF_TOK + 36864;          // f32  [9216]     (zeroed)
constexpr size_t ZERO_BEG = OFF_KPP;
constexpr size_t ZERO_LEN = 155904;                   // through GSL end
constexpr size_t OFF_OFFP = ZERO_BEG + ZERO_LEN;      // int [16]
constexpr size_t OFF_IDX2 = OFF_OFFP + 128;           // int [4096][2]
constexpr size_t OFF_G2   = OFF_IDX2 + 32768;         // f32 [4096][2]
constexpr size_t OFF_INV  = OFF_G2 + 32768;           // int [4096][2]
constexpr size_t SMALL_END = OFF_INV + 32768;

constexpr size_t A_OFF_FCB = SMALL_END;                    // bf16 [8][4096][1024]
constexpr size_t A_OFF_PO  = A_OFF_FCB;                    // f32  [9216][1024] (alias; fcb dead by proj)
constexpr size_t A_OFF_PJB = A_OFF_FCB + 67108864;         // bf16 [8][1024][4096]
constexpr size_t A_OFF_H2  = A_OFF_PJB + 67108864;         // bf16 [9216][4096]
constexpr size_t WS_FULL   = A_OFF_H2 + 75497472;          // ~210.3 MiB (proven)

__device__ inline unsigned short f2bf(float f) {
  __hip_bfloat16 h = __float2bfloat16(f);
  return __builtin_bit_cast(unsigned short, h);
}

__device__ __forceinline__ void gload16(const void* g, void* l) {
  __builtin_amdgcn_global_load_lds(
      (const __attribute__((address_space(1))) unsigned int*)g,
      (__attribute__((address_space(3))) unsigned int*)l, 16, 0, 0);
}

// ---------------- x + router_w fp32 -> bf16, plus zero-init (blocks 160..167) ----------------
__global__ __launch_bounds__(256) void k_cvt_xw(
    const float* __restrict__ x, const float* __restrict__ rw,
    unsigned short* __restrict__ xb, unsigned short* __restrict__ wb,
    char* __restrict__ zbase) {
  const int b = (int)blockIdx.x;
  if (b >= 160) {
    const f32x4 zv = {0.f, 0.f, 0.f, 0.f};
    size_t o = ((size_t)(b - 160) * 256 + threadIdx.x) * 16;
    for (; o < ZERO_LEN; o += (size_t)8 * 256 * 16)
      *(f32x4*)(zbase + o) = zv;
    return;
  }
  int u = b * 8;
  const f32x4* s; u16x4* d; int base;
  if (u < 1024) { s = (const f32x4*)x;  d = (u16x4*)xb; base = u; }
  else          { s = (const f32x4*)rw; d = (u16x4*)wb; base = u - 1024; }
  int j = base * 1024 + (int)threadIdx.x;
#pragma unroll 2
  for (int k = 0; k < 8; ++k, j += 1024) {
    f32x4 v0 = __builtin_nontemporal_load(s + j);
    f32x4 v1 = __builtin_nontemporal_load(s + j + 256);
    f32x4 v2 = __builtin_nontemporal_load(s + j + 512);
    f32x4 v3 = __builtin_nontemporal_load(s + j + 768);
    u16x4 o0 = { f2bf(v0.x), f2bf(v0.y), f2bf(v0.z), f2bf(v0.w) };
    u16x4 o1 = { f2bf(v1.x), f2bf(v1.y), f2bf(v1.z), f2bf(v1.w) };
    u16x4 o2 = { f2bf(v2.x), f2bf(v2.y), f2bf(v2.z), f2bf(v2.w) };
    u16x4 o3 = { f2bf(v3.x), f2bf(v3.y), f2bf(v3.z), f2bf(v3.w) };
    __builtin_nontemporal_store(o0, d + j);
    __builtin_nontemporal_store(o1, d + j + 256);
    __builtin_nontemporal_store(o2, d + j + 512);
    __builtin_nontemporal_store(o3, d + j + 768);
  }
}

// ================= MEGA: qt (0..255) | colsum (256..319) | fc_w cvt (320..1343) =================
constexpr int QTG = 256, CSG = 64, CVG = 1024;

__global__ __launch_bounds__(256) void k_mega(
    const unsigned short* __restrict__ xb, const unsigned short* __restrict__ wb,
    float* __restrict__ sumsq,
    const float* __restrict__ W, const float* __restrict__ keys,
    const int* __restrict__ depth, double* __restrict__ kpp,
    const float* __restrict__ fw, unsigned short* __restrict__ fcb) {
  __shared__ alignas(16) char smem[65536];
  const int bid = (int)blockIdx.x;
  const int tid = threadIdx.x;

  if (bid < QTG) {
    constexpr int KD = DIM_V, GNB = DIM_V / 128, NT = KD / 64, q = QTG >> 3;
    const int idp = (bid & 7) * q + (bid >> 3);
    const int n0 = (idp % GNB) * 128, m0 = (idp / GNB) * 128;
    const unsigned short* Bp = wb + (size_t)n0 * KD;
    const int wid = tid >> 6, lane = tid & 63;
    const int wr = (wid >> 1) * 64, wc = (wid & 1) * 64;
    const int rql  = tid >> 3;
    const int swc8 = ((tid & 7) ^ ((tid >> 3) & 7)) * 8;
    const int frow = lane & 15, fsl = lane >> 4, fkey = lane & 7;

    auto stage = [&](int k0s, unsigned db) {
#pragma unroll
      for (int p = 0; p < 4; ++p)
        gload16(xb + (size_t)(m0 + p * 32 + rql) * KD + k0s + swc8,
                smem + db + p * 4096 + wid * 1024);
#pragma unroll
      for (int p = 0; p < 4; ++p)
        gload16(Bp + (size_t)(p * 32 + rql) * KD + k0s + swc8,
                smem + db + 16384 + p * 4096 + wid * 1024);
    };

    f32x4 acc[4][4] = {};
    stage(0, 0);
#pragma unroll 2
    for (int t = 0; t < NT; ++t) {
      int tn = t + 1; if (tn == NT) tn = 0;
      stage(tn * 64, (unsigned)((t + 1) & 1) * 32768u);
      asm volatile("s_waitcnt vmcnt(8)" ::: "memory");
      __builtin_amdgcn_s_barrier();
      __builtin_amdgcn_sched_barrier(0);
      const unsigned Ab = (unsigned)(t & 1) * 32768u, Bb = Ab + 16384u;
      s16x8 af[2][4], bfr[2][4];
#pragma unroll
      for (int kk2 = 0; kk2 < 2; ++kk2) {
        const unsigned so = (unsigned)(((fsl + kk2 * 4) ^ fkey) << 4);
#pragma unroll
        for (int m = 0; m < 4; ++m)
          af[kk2][m] = *(const s16x8*)(smem + Ab + (unsigned)(wr + m * 16 + frow) * 128 + so);
#pragma unroll
        for (int n = 0; n < 4; ++n)
          bfr[kk2][n] = *(const s16x8*)(smem + Bb + (unsigned)(wc + n * 16 + frow) * 128 + so);
      }
      __builtin_amdgcn_s_setprio(1);
#pragma unroll
      for (int kk2 = 0; kk2 < 2; ++kk2)
#pragma unroll
        for (int m = 0; m < 4; ++m)
#pragma unroll
          for (int n = 0; n < 4; ++n)
            acc[m][n] = __builtin_amdgcn_mfma_f32_16x16x32_bf16(af[kk2][m], bfr[kk2][n],
                                                                acc[m][n], 0, 0, 0);
      __builtin_amdgcn_s_setprio(0);
      __builtin_amdgcn_sched_barrier(0);
      __builtin_amdgcn_s_barrier();
    }
#pragma unroll
    for (int m = 0; m < 4; ++m)
#pragma unroll
      for (int j = 0; j < 4; ++j) {
        const int grow = m0 + wr + m * 16 + (lane >> 4) * 4 + j;
        float s = 0.f;
#pragma unroll
        for (int n = 0; n < 4; ++n) { float v = acc[m][n][j]; s += v * v; }
        s += __shfl_xor(s, 1, 64); s += __shfl_xor(s, 2, 64);
        s += __shfl_xor(s, 4, 64); s += __shfl_xor(s, 8, 64);
        if ((lane & 15) == 0) atomicAdd(&sumsq[grow], s);
      }
  } else if (bid < QTG + CSG) {
    double (*rks)[64] = (double(*)[64])smem;
    const int cid = bid - QTG;
    const int d0 = (cid >> 2) * 64;
    if (tid < 64) {
      const int d = d0 + tid;
      const int dep = depth[0];
      const bool lower = d < 512;
      const int i = lower ? d : d - 512;
      double p = pow(10000.0, (double)i / 512.0);
      float invf = 1.0f / (float)p;
      float ff = (float)dep * invf;
      float rr = (float)(15 - dep) * invf;
      float cf  = (float)cos((double)ff);
      float sf  = (float)sin((double)ff);
      float rcf = (float)cos((double)rr);
      float rsf = (float)sin((double)rr);
      for (int e = 0; e < NEXP; ++e) {
        double k1 = (double)keys[e * DIM_V + i];
        double k2 = (double)keys[e * DIM_V + 512 + i];
        rks[e][tid] = lower ? ((double)cf * k1 - (double)rsf * k2)
                            : ((double)sf * k1 + (double)rcf * k2);
      }
    }
    __syncthreads();
    const int j = (cid & 3) * 256 + tid;
    double acc[NEXP] = {};
    for (int dd = 0; dd < 64; ++dd) {
      double w = (double)W[(size_t)(d0 + dd) * DIM_V + j];
#pragma unroll
      for (int e = 0; e < NEXP; ++e) acc[e] += w * rks[e][dd];
    }
    for (int e = 0; e < NEXP; ++e) atomicAdd(&kpp[e * DIM_V + j], acc[e]);
  } else {
    int u = (bid - QTG - CSG) * 8;
    const f32x4* s = (const f32x4*)fw;
    u16x4* d = (u16x4*)fcb;
    int j = u * 1024 + tid;
#pragma unroll 2
    for (int k = 0; k < 8; ++k, j += 1024) {
      f32x4 v0 = __builtin_nontemporal_load(s + j);
      f32x4 v1 = __builtin_nontemporal_load(s + j + 256);
      f32x4 v2 = __builtin_nontemporal_load(s + j + 512);
      f32x4 v3 = __builtin_nontemporal_load(s + j + 768);
      u16x4 o0 = { f2bf(v0.x), f2bf(v0.y), f2bf(v0.z), f2bf(v0.w) };
      u16x4 o1 = { f2bf(v1.x), f2bf(v1.y), f2bf(v1.z), f2bf(v1.w) };
      u16x4 o2 = { f2bf(v2.x), f2bf(v2.y), f2bf(v2.z), f2bf(v2.w) };
      u16x4 o3 = { f2bf(v3.x), f2bf(v3.y), f2bf(v3.z), f2bf(v3.w) };
      __builtin_nontemporal_store(o0, d + j);
      __builtin_nontemporal_store(o1, d + j + 256);
      __builtin_nontemporal_store(o2, d + j + 512);
      __builtin_nontemporal_store(o3, d + j + 768);
    }
  }
}

// ---------------- gate (blocks 0..1023) | proj_w cvt (1024..2047) ----------------
__global__ __launch_bounds__(256) void k_gate2(
    const float* __restrict__ x, const double* __restrict__ kpp,
    const float* __restrict__ sumsq, const float* __restrict__ bias,
    int* __restrict__ idx2, float* __restrict__ gates2, int* __restrict__ counts,
    const float* __restrict__ pw, unsigned short* __restrict__ pjb) {
  const int bid = (int)blockIdx.x;
  if (bid >= 1024) {
    int u = (bid - 1024) * 8;
    const f32x4* s = (const f32x4*)pw;
    u16x4* d = (u16x4*)pjb;
    int j = u * 1024 + (int)threadIdx.x;
#pragma unroll 2
    for (int k = 0; k < 8; ++k, j += 1024) {
      f32x4 v0 = __builtin_nontemporal_load(s + j);
      f32x4 v1 = __builtin_nontemporal_load(s + j + 256);
      f32x4 v2 = __builtin_nontemporal_load(s + j + 512);
      f32x4 v3 = __builtin_nontemporal_load(s + j + 768);
      u16x4 o0 = { f2bf(v0.x), f2bf(v0.y), f2bf(v0.z), f2bf(v0.w) };
      u16x4 o1 = { f2bf(v1.x), f2bf(v1.y), f2bf(v1.z), f2bf(v1.w) };
      u16x4 o2 = { f2bf(v2.x), f2bf(v2.y), f2bf(v2.z), f2bf(v2.w) };
      u16x4 o3 = { f2bf(v3.x), f2bf(v3.y), f2bf(v3.z), f2bf(v3.w) };
      __builtin_nontemporal_store(o0, d + j);
      __builtin_nontemporal_store(o1, d + j + 256);
      __builtin_nontemporal_store(o2, d + j + 512);
      __builtin_nontemporal_store(o3, d + j + 768);
    }
    return;
  }
  int wave = (bid * 256 + (int)threadIdx.x) >> 6;
  int lane = threadIdx.x & 63;
  if (wave >= N_TOK) return;
  const float4* xr = (const float4*)(x + (size_t)wave * DIM_V);
  double a[NEXP] = {};
#pragma unroll
  for (int j = 0; j < 4; ++j) {
    int c = lane + 64 * j;
    float4 v = xr[c];
#pragma unroll
    for (int e = 0; e < NEXP; ++e) {
      const double* kp = kpp + (size_t)e * DIM_V + c * 4;
      a[e] += (double)v.x * kp[0] + (double)v.y * kp[1] +
              (double)v.z * kp[2] + (double)v.w * kp[3];
    }
  }
#pragma unroll
  for (int e = 0; e < NEXP; ++e)
    for (int d = 1; d < 64; d <<= 1) a[e] += __shfl_xor(a[e], d, 64);
  if (lane == 0) {
    float s = rsqrtf(sumsq[wave] * (1.0f / 1024.0f) + 1.1920928955078125e-7f);
    float z[NEXP], b[NEXP];
#pragma unroll
    for (int e = 0; e < NEXP; ++e) {
      z[e] = (float)(a[e] * (double)s * (1.0 / 32.0));
      b[e] = z[e] + bias[e];
    }
    int i1 = 0;
    for (int e = 1; e < NEXP; ++e) if (b[e] > b[i1]) i1 = e;
    int i2 = -1;
    for (int e = 0; e < NEXP; ++e) if (e != i1 && (i2 < 0 || b[e] > b[i2])) i2 = e;
    float g1 = 1.f / (1.f + expf(-z[i1]));
    float g2 = 1.f / (1.f + expf(-z[i2]));
    float sm = fmaxf(g1 + g2, 1e-9f);
    idx2[wave * 2] = i1; idx2[wave * 2 + 1] = i2;
    gates2[wave * 2] = g1 / sm; gates2[wave * 2 + 1] = g2 / sm;
    atomicAdd(&counts[i1], 1); atomicAdd(&counts[i2], 1);
  }
}

// ---------------- scatter tokens to slots (prefix computed locally) ----------------
__global__ void k_scatter(const int* __restrict__ idx2, const float* __restrict__ gates2,
                          const int* __restrict__ counts, int* __restrict__ cursor,
                          int* __restrict__ tok, float* __restrict__ gsl,
                          int* __restrict__ inv, int* __restrict__ offp_out) {
  int off[NEXP + 1];
  off[0] = 0;
  for (int e = 0; e < NEXP; ++e) off[e + 1] = off[e] + ((counts[e] + 127) & ~127);
  int n = blockIdx.x * 256 + threadIdx.x;
  if (blockIdx.x == 0 && threadIdx.x == 0)
    for (int e = 0; e <= NEXP; ++e) offp_out[e] = off[e];
  if (n >= N_TOK) return;
  for (int r = 0; r < 2; ++r) {
    int e = idx2[n * 2 + r];
    int pos = atomicAdd(&cursor[e], 1);
    int slot = off[e] + pos;
    tok[slot] = n; gsl[slot] = gates2[n * 2 + r]; inv[n * 2 + r] = slot;
  }
}

// ================= fc: 256x256x64 grouped GEMM, 8 waves, 128KiB LDS =================
__global__ __launch_bounds__(512) void k_fc256(
    const unsigned short* __restrict__ xb,
    const unsigned short* __restrict__ fcb,
    const int* __restrict__ offp, const int* __restrict__ tok,
    unsigned short* __restrict__ h2) {
  constexpr int KD = DIM_V;     // 1024
  constexpr int NT = KD / 64;   // 16
  const int G = gridDim.x, q = G >> 3;                 // G % 8 == 0
  const int idp = ((int)blockIdx.x & 7) * q + ((int)blockIdx.x >> 3);
  const int bx = idp >> 4;                             // 256-row block index
  const int n0 = (idp & 15) * 256;
  int c = 0, e = 0, m0 = -1;
  for (e = 0; e < NEXP; ++e) {
    int nb = (offp[e + 1] - offp[e] + 255) >> 8;
    if (bx < c + nb) { m0 = offp[e] + (bx - c) * 256; break; }
    c += nb;
  }
  if (m0 < 0) return;
  const int segend = offp[e + 1];
  const unsigned short* Bp = fcb + ((size_t)e * HID + n0) * KD;

  __shared__ alignas(16) char smem[131072];            // 2 x (A 32K + B 32K)
  const int tid = threadIdx.x, wid = tid >> 6, lane = tid & 63;
  const int wr = (wid >> 2) * 128, wcc = (wid & 3) * 64;
  const int swc8 = ((tid & 7) ^ ((tid >> 3) & 7)) * 8;
  const int frow = lane & 15, fsl = lane >> 4, fkey = lane & 7;

  int arow[4];
#pragma unroll
  for (int p = 0; p < 4; ++p) {
    int rr = m0 + p * 64 + (tid >> 3);
    arow[p] = tok[rr < NSLOT ? rr : NSLOT - 1];
  }

  auto stage = [&](int k0s, unsigned db) {
#pragma unroll
    for (int p = 0; p < 4; ++p)
      gload16(xb + (size_t)arow[p] * KD + k0s + swc8,
              smem + db + p * 8192 + wid * 1024);
#pragma unroll
    for (int p = 0; p < 4; ++p)
      gload16(Bp + (size_t)(p * 64 + (tid >> 3)) * KD + k0s + swc8,
              smem + db + 32768 + p * 8192 + wid * 1024);
  };

  f32x4 acc[8][4] = {};
  stage(0, 0);
  for (int t = 0; t < NT; ++t) {
    int tn = t + 1; if (tn == NT) tn = 0;
    stage(tn * 64, (unsigned)((t + 1) & 1) * 65536u);
    asm volatile("s_waitcnt vmcnt(8)" ::: "memory");
    __builtin_amdgcn_s_barrier();
    __builtin_amdgcn_sched_barrier(0);
    const unsigned Ab = (unsigned)(t & 1) * 65536u, Bb = Ab + 32768u;
#pragma unroll
    for (int kk2 = 0; kk2 < 2; ++kk2) {
      const unsigned so = (unsigned)(((fsl + kk2 * 4) ^ fkey) << 4);
      s16x8 af[8], bfr[4];
#pragma unroll
      for (int m = 0; m < 8; ++m)
        af[m] = *(const s16x8*)(smem + Ab + (unsigned)(wr + m * 16 + frow) * 128 + so);
#pragma unroll
      for (int n = 0; n < 4; ++n)
        bfr[n] = *(const s16x8*)(smem + Bb + (unsigned)(wcc + n * 16 + frow) * 128 + so);
      __builtin_amdgcn_s_setprio(1);
#pragma unroll
      for (int m = 0; m < 8; ++m)
#pragma unroll
        for (int n = 0; n < 4; ++n)
          acc[m][n] = __builtin_amdgcn_mfma_f32_16x16x32_bf16(af[m], bfr[n], acc[m][n], 0, 0, 0);
      __builtin_amdgcn_s_setprio(0);
    }
    __builtin_amdgcn_sched_barrier(0);
    __builtin_amdgcn_s_barrier();
  }
#pragma unroll
  for (int m = 0; m < 8; ++m)
#pragma unroll
    for (int j = 0; j < 4; ++j) {
      const int grow = m0 + wr + m * 16 + (lane >> 4) * 4 + j;
      if (grow < segend) {
#pragma unroll
        for (int n = 0; n < 4; ++n) {
          float v = acc[m][n][j];
          v = v > 0.f ? v * v : 0.f;
          h2[(size_t)grow * HID + n0 + wcc + n * 16 + (lane & 15)] = f2bf(v);
        }
      }
    }
}

// ================= proj: 128x128x64, 4 waves, 2-buf counted-vmcnt (R3-proven) =================
__global__ __launch_bounds__(256) void k_proj(
    const unsigned short* __restrict__ h2,
    const unsigned short* __restrict__ pjb,
    const int* __restrict__ offp, const float* __restrict__ gsl,
    float* __restrict__ po) {
  constexpr int KD  = HID;          // 4096
  constexpr int GNB = DIM_V / 128;  // 8
  constexpr int NT  = KD / 64;      // 64
  const int G = gridDim.x, q = G >> 3;
  const int idp = ((int)blockIdx.x & 7) * q + ((int)blockIdx.x >> 3);
  const int n0 = (idp % GNB) * 128, m0 = (idp / GNB) * 128;
  if (m0 >= offp[NEXP]) return;
  int e = 0; while (e < NEXP - 1 && m0 >= offp[e + 1]) ++e;
  const unsigned short* Bp = pjb + ((size_t)e * DIM_V + n0) * KD;

  __shared__ alignas(16) char smem[65536];
  const int tid = threadIdx.x, wid = tid >> 6, lane = tid & 63;
  const int wr = (wid >> 1) * 64, wc = (wid & 1) * 64;
  const int rql  = tid >> 3;
  const int swc8 = ((tid & 7) ^ ((tid >> 3) & 7)) * 8;
  const int frow = lane & 15, fsl = lane >> 4, fkey = lane & 7;

  auto stage = [&](int k0s, unsigned db) {
#pragma unroll
    for (int p = 0; p < 4; ++p)
      gload16(h2 + (size_t)(m0 + p * 32 + rql) * KD + k0s + swc8,
              smem + db + p * 4096 + wid * 1024);
#pragma unroll
    for (int p = 0; p < 4; ++p)
      gload16(Bp + (size_t)(p * 32 + rql) * KD + k0s + swc8,
              smem + db + 16384 + p * 4096 + wid * 1024);
  };

  f32x4 acc[4][4] = {};
  stage(0, 0);
#pragma unroll 2
  for (int t = 0; t < NT; ++t) {
    int tn = t + 1; if (tn == NT) tn = 0;
    stage(tn * 64, (unsigned)((t + 1) & 1) * 32768u);
    asm volatile("s_waitcnt vmcnt(8)" ::: "memory");
    __builtin_amdgcn_s_barrier();
    __builtin_amdgcn_sched_barrier(0);
    const unsigned Ab = (unsigned)(t & 1) * 32768u, Bb = Ab + 16384u;
    s16x8 af[2][4], bfr[2][4];
#pragma unroll
    for (int kk2 = 0; kk2 < 2; ++kk2) {
      const unsigned so = (unsigned)(((fsl + kk2 * 4) ^ fkey) << 4);
#pragma unroll
      for (int m = 0; m < 4; ++m)
        af[kk2][m] = *(const s16x8*)(smem + Ab + (unsigned)(wr + m * 16 + frow) * 128 + so);
#pragma unroll
      for (int n = 0; n < 4; ++n)
        bfr[kk2][n] = *(const s16x8*)(smem + Bb + (unsigned)(wc + n * 16 + frow) * 128 + so);
    }
    __builtin_amdgcn_s_setprio(1);
#pragma unroll
    for (int kk2 = 0; kk2 < 2; ++kk2)
#pragma unroll
      for (int m = 0; m < 4; ++m)
#pragma unroll
        for (int n = 0; n < 4; ++n)
          acc[m][n] = __builtin_amdgcn_mfma_f32_16x16x32_bf16(af[kk2][m], bfr[kk2][n],
                                                              acc[m][n], 0, 0, 0);
    __builtin_amdgcn_s_setprio(0);
    __builtin_amdgcn_sched_barrier(0);
    __builtin_amdgcn_s_barrier();
  }

#pragma unroll
  for (int m = 0; m < 4; ++m)
#pragma unroll
    for (int j = 0; j < 4; ++j) {
      const int grow = m0 + wr + m * 16 + (lane >> 4) * 4 + j;
      const float g = gsl[grow];
#pragma unroll
      for (int n = 0; n < 4; ++n)
        po[(size_t)grow * DIM_V + n0 + wc + n * 16 + (lane & 15)] = acc[m][n][j] * g;
    }
}

// ---------------- combine: y[n] = po[slot1] + po[slot2] ----------------
__global__ void k_combine(const float* __restrict__ po, const int* __restrict__ inv,
                          float* __restrict__ y) {
  const int total = N_TOK * (DIM_V / 4);
  for (int i = blockIdx.x * blockDim.x + threadIdx.x; i < total;
       i += gridDim.x * blockDim.x) {
    int n = i >> 8, c = i & 255;
    int s1 = inv[n * 2], s2 = inv[n * 2 + 1];
    float4 a = ((const float4*)(po + (size_t)s1 * DIM_V))[c];
    float4 b = ((const float4*)(po + (size_t)s2 * DIM_V))[c];
    float4 o; o.x = a.x + b.x; o.y = a.y + b.y; o.z = a.z + b.z; o.w = a.w + b.w;
    ((float4*)(y + (size_t)n * DIM_V))[c] = o;
  }
}

extern "C" void kernel_launch(void* const* d_in, const int* in_sizes, int n_in,
                              void* d_out, int out_size, void* d_ws, size_t ws_size,
                              hipStream_t stream) {
  if (ws_size < WS_FULL) return;
  const float* x      = (const float*)d_in[0];
  const float* rw     = (const float*)d_in[1];
  const float* keys   = (const float*)d_in[2];
  const float* bias   = (const float*)d_in[3];
  const float* fc_w   = (const float*)d_in[4];
  const float* proj_w = (const float*)d_in[5];
  const int*   depth  = (const int*)d_in[6];
  char* ws = (char*)d_ws;
  unsigned short* xb  = (unsigned short*)(ws + OFF_XB);
  unsigned short* wb  = (unsigned short*)(ws + OFF_WB);
  double* kpp   = (double*)(ws + OFF_KPP);
  float*  ssq   = (float*)(ws + OFF_SSQ);
  int*    cnt   = (int*)(ws + OFF_CNT);
  int*    cur   = (int*)(ws + OFF_CUR);
  int*    tok   = (int*)(ws + OFF_TOK);
  float*  gsl   = (float*)(ws + OFF_GSL);
  int*    offp  = (int*)(ws + OFF_OFFP);
  int*    idx2  = (int*)(ws + OFF_IDX2);
  float*  g2    = (float*)(ws + OFF_G2);
  int*    inv   = (int*)(ws + OFF_INV);
  unsigned short* fcb = (unsigned short*)(ws + A_OFF_FCB);
  unsigned short* pjb = (unsigned short*)(ws + A_OFF_PJB);
  unsigned short* h2  = (unsigned short*)(ws + A_OFF_H2);
  float*  po    = (float*)(ws + A_OFF_PO);
  float*  y     = (float*)d_out;

  k_cvt_xw<<<168, 256, 0, stream>>>(x, rw, xb, wb, ws + ZERO_BEG);
  k_mega<<<QTG + CSG + CVG, 256, 0, stream>>>(xb, wb, ssq, rw, keys, depth, kpp,
                                              fc_w, fcb);
  k_gate2<<<2048, 256, 0, stream>>>(x, kpp, ssq, bias, idx2, g2, cnt, proj_w, pjb);
  k_scatter<<<16, 256, 0, stream>>>(idx2, g2, cnt, cur, tok, gsl, inv, offp);
  k_fc256<<<dim3(44 * 16), 512, 0, stream>>>(xb, fcb, offp, tok, h2);
  k_proj<<<dim3(72 * 8), 256, 0, stream>>>(h2, pjb, offp, gsl, po);
  k_combine<<<2048, 256, 0, stream>>>(po, inv, y);
}